// Round 3
// baseline (777.517 us; speedup 1.0000x reference)
//
#include <hip/hip_runtime.h>
#include <cstddef>

#define B_ 64
#define T_ 256
#define C_ 2048
#define H_ 512
#define O_ 11
#define THRESH 1.0f
#define LEAK_ 0.003f
#define OLEAK_ 0.0015f

typedef float v2f __attribute__((ext_vector_type(2)));

// ---------------------------------------------------------------------------
// Kernel 1: transpose w_rec (H x H) -> w_recT (coalesced recurrent gather).
// ---------------------------------------------------------------------------
__global__ __launch_bounds__(256) void transpose_wrec(const float* __restrict__ w,
                                                      float* __restrict__ wt) {
    __shared__ float tile[32][33];
    int tx = threadIdx.x, ty = threadIdx.y;           // block (32, 8)
    int x = blockIdx.x * 32 + tx;
    int y = blockIdx.y * 32 + ty;
#pragma unroll
    for (int i = 0; i < 32; i += 8)
        tile[ty + i][tx] = w[(size_t)(y + i) * H_ + x];
    __syncthreads();
    int x2 = blockIdx.y * 32 + tx;
    int y2 = blockIdx.x * 32 + ty;
#pragma unroll
    for (int i = 0; i < 32; i += 8)
        wt[(size_t)(y2 + i) * H_ + x2] = tile[tx][ty + i];
}

// ---------------------------------------------------------------------------
// Kernel 2: split-K GEMM  P[s] = X @ w1^T.
// BM=256 x BN=128 tile, BK=16, 256 threads, 16x8 microtile (2.67 FLOP per
// LDS byte -> VALU-bound, not LDS-BW-bound). LDS rows padded +4 floats:
// keeps 16B alignment, turns 4-way staging-write conflicts into free 2-way.
// float2 acc -> v_pk_fma_f32.
// ---------------------------------------------------------------------------
#define BM 256
#define BN 128
#define BK 16

template <int S>
__global__ __launch_bounds__(256, 2) void gemm_ff(const float* __restrict__ A,
                                                  const float* __restrict__ Bw,
                                                  float* __restrict__ Pout) {
    const int K = C_;
    const int N = H_;
    const int kLen  = C_ / S;
    const int kBase = blockIdx.z * kLen;

    __shared__ float As[BK][BM + 4];
    __shared__ float Bs[BK][BN + 4];

    const int t  = threadIdx.x;
    const int tx = t & 15;        // n-dir: 16 threads x TN=8 -> 128
    const int ty = t >> 4;        // m-dir: 16 threads x TM=16 -> 256
    const int lr = t >> 2;        // load row 0..63
    const int lc = (t & 3) * 4;   // load col 0,4,8,12

    const float* Aptr = A  + (size_t)(blockIdx.y * BM + lr) * K + kBase + lc;
    const float* Bptr = Bw + (size_t)(blockIdx.x * BN + lr) * K + kBase + lc;

    v2f acc[16][4];
#pragma unroll
    for (int i = 0; i < 16; ++i)
#pragma unroll
        for (int j = 0; j < 4; ++j) acc[i][j] = (v2f){0.f, 0.f};

    for (int k0 = 0; k0 < kLen; k0 += BK) {
        float4 a0 = *(const float4*)(Aptr);
        float4 a1 = *(const float4*)(Aptr + (size_t)64  * K);
        float4 a2 = *(const float4*)(Aptr + (size_t)128 * K);
        float4 a3 = *(const float4*)(Aptr + (size_t)192 * K);
        float4 b0 = *(const float4*)(Bptr);
        float4 b1 = *(const float4*)(Bptr + (size_t)64 * K);
        Aptr += BK; Bptr += BK;

        __syncthreads();
        As[lc + 0][lr]       = a0.x; As[lc + 1][lr]       = a0.y;
        As[lc + 2][lr]       = a0.z; As[lc + 3][lr]       = a0.w;
        As[lc + 0][lr + 64]  = a1.x; As[lc + 1][lr + 64]  = a1.y;
        As[lc + 2][lr + 64]  = a1.z; As[lc + 3][lr + 64]  = a1.w;
        As[lc + 0][lr + 128] = a2.x; As[lc + 1][lr + 128] = a2.y;
        As[lc + 2][lr + 128] = a2.z; As[lc + 3][lr + 128] = a2.w;
        As[lc + 0][lr + 192] = a3.x; As[lc + 1][lr + 192] = a3.y;
        As[lc + 2][lr + 192] = a3.z; As[lc + 3][lr + 192] = a3.w;
        Bs[lc + 0][lr]       = b0.x; Bs[lc + 1][lr]       = b0.y;
        Bs[lc + 2][lr]       = b0.z; Bs[lc + 3][lr]       = b0.w;
        Bs[lc + 0][lr + 64]  = b1.x; Bs[lc + 1][lr + 64]  = b1.y;
        Bs[lc + 2][lr + 64]  = b1.z; Bs[lc + 3][lr + 64]  = b1.w;
        __syncthreads();

#pragma unroll
        for (int k = 0; k < BK; ++k) {
            float4 af0 = *(const float4*)&As[k][ty * 8];
            float4 af1 = *(const float4*)&As[k][ty * 8 + 4];
            float4 af2 = *(const float4*)&As[k][128 + ty * 8];
            float4 af3 = *(const float4*)&As[k][128 + ty * 8 + 4];
            float4 blo = *(const float4*)&Bs[k][tx * 4];
            float4 bhi = *(const float4*)&Bs[k][64 + tx * 4];
            v2f b0v = {blo.x, blo.y}, b1v = {blo.z, blo.w};
            v2f b2v = {bhi.x, bhi.y}, b3v = {bhi.z, bhi.w};
            float av[16] = {af0.x, af0.y, af0.z, af0.w, af1.x, af1.y, af1.z, af1.w,
                            af2.x, af2.y, af2.z, af2.w, af3.x, af3.y, af3.z, af3.w};
#pragma unroll
            for (int i = 0; i < 16; ++i) {
                v2f ai = {av[i], av[i]};
                acc[i][0] += ai * b0v;
                acc[i][1] += ai * b1v;
                acc[i][2] += ai * b2v;
                acc[i][3] += ai * b3v;
            }
        }
    }

    float* P = Pout + (size_t)blockIdx.z * ((size_t)B_ * T_ * H_);
#pragma unroll
    for (int i = 0; i < 16; ++i) {
        int row = blockIdx.y * BM + (i < 8 ? ty * 8 + i : 128 + ty * 8 + (i - 8));
        float* Cp = P + (size_t)row * N + blockIdx.x * BN;
        float4 c0 = {acc[i][0].x, acc[i][0].y, acc[i][1].x, acc[i][1].y};
        float4 c1 = {acc[i][2].x, acc[i][2].y, acc[i][3].x, acc[i][3].y};
        *(float4*)(Cp + tx * 4)      = c0;
        *(float4*)(Cp + 64 + tx * 4) = c1;
    }
}

// ---------------------------------------------------------------------------
// Kernel 2b: in-place split-K reduce: P0 += P1 + ... (s ascending, matches
// previous deterministic order). I1 aliases P0, so no extra workspace.
// ---------------------------------------------------------------------------
template <int S>
__global__ __launch_bounds__(256) void reduce_parts(float* __restrict__ P) {
    const size_t n = (size_t)B_ * T_ * H_;
    size_t i = ((size_t)blockIdx.x * 256 + threadIdx.x) * 4;
    if (i >= n) return;
    float4 a = *(float4*)(P + i);
#pragma unroll
    for (int s = 1; s < S; ++s) {
        float4 bq = *(const float4*)(P + (size_t)s * n + i);
        a.x += bq.x; a.y += bq.y; a.z += bq.z; a.w += bq.w;
    }
    *(float4*)(P + i) = a;
}

// ---------------------------------------------------------------------------
// Kernel 3: recurrent LIF scan — ONE WAVE per batch element, 8 neurons/lane
// (h = r*64 + lane). Zero barriers: spike sets live as 8 x 64-bit ballot
// masks in registers; recurrent current = per-spike coalesced row gather
// from w_recT (L2-hot, 1 MB); output neurons on lanes 0..10 read w2 rows
// (22 KB, L1-hot). I1 prefetched one step ahead.
// ---------------------------------------------------------------------------
__global__ __launch_bounds__(64) void snn_rec(const float* __restrict__ I1,
                                              const float* __restrict__ wrT,
                                              const float* __restrict__ w2,
                                              float* __restrict__ out) {
    const int b = blockIdx.x;
    const int L = threadIdx.x;

    const float* i1p = I1 + (size_t)b * T_ * H_ + L;
    const float* wrL = wrT + L;
    const float* w2L = w2 + (size_t)(L < O_ ? L : 0) * H_;

    float v1[8], pf[8];
    unsigned long long masks[8];
#pragma unroll
    for (int r = 0; r < 8; ++r) { v1[r] = 0.f; masks[r] = 0ull; pf[r] = i1p[r * 64]; }
    float v2 = 0.f, osum = 0.f;

    for (int t = 0; t < T_; ++t) {
        float acc[8];
#pragma unroll
        for (int r = 0; r < 8; ++r) acc[r] = pf[r] - LEAK_;

        // prefetch next step's feedforward current
        const float* nx = i1p + (size_t)((t + 1 < T_) ? t + 1 : t) * H_;
#pragma unroll
        for (int r = 0; r < 8; ++r) pf[r] = nx[r * 64];

        // recurrent gather over previous step's spike masks (sorted j order)
#pragma unroll
        for (int r2 = 0; r2 < 8; ++r2) {
            unsigned long long m = masks[r2];
            while (m) {
                int j = (r2 << 6) + __builtin_ctzll(m);
                m &= (m - 1);
                const float* wj = wrL + (size_t)j * H_;
#pragma unroll
                for (int r = 0; r < 8; ++r) acc[r] += wj[r * 64];
            }
        }

        // membrane update, spike, subtractive reset
#pragma unroll
        for (int r = 0; r < 8; ++r) v1[r] += acc[r];
#pragma unroll
        for (int r = 0; r < 8; ++r) {
            masks[r] = __ballot(v1[r] >= THRESH);
            if (v1[r] >= THRESH) v1[r] -= THRESH;
        }

        // output neurons (lanes 0..10), current step's spikes, sorted j order
        float s = 0.f;
        if (L < O_) {
#pragma unroll
            for (int r2 = 0; r2 < 8; ++r2) {
                unsigned long long m = masks[r2];
                while (m) {
                    int j = (r2 << 6) + __builtin_ctzll(m);
                    m &= (m - 1);
                    s += w2L[j];
                }
            }
        }
        v2 = v2 + s - OLEAK_;
        v2 = v2 > 0.f ? v2 : 0.f;
        osum += v2;
    }
    if (L < O_) out[b * O_ + L] = osum * (1.0f / (float)T_);
}

// ---------------------------------------------------------------------------
extern "C" void kernel_launch(void* const* d_in, const int* in_sizes, int n_in,
                              void* d_out, int out_size, void* d_ws, size_t ws_size,
                              hipStream_t stream) {
    const float* x     = (const float*)d_in[0];   // (B,T,C)
    const float* w1    = (const float*)d_in[1];   // (H,C)
    const float* w_rec = (const float*)d_in[2];   // (H,H)
    const float* w2    = (const float*)d_in[3];   // (O,H)
    float* out = (float*)d_out;                   // (B,O)

    const size_t PART = (size_t)B_ * T_ * H_ * sizeof(float);   // 32 MB
    const size_t WRT  = (size_t)H_ * H_ * sizeof(float);        // 1 MB

    int S = 1;
    if (ws_size >= 4 * PART + WRT) S = 4;
    else if (ws_size >= 2 * PART + WRT) S = 2;

    float* P   = (float*)d_ws;                      // I1 aliases P0 after reduce
    float* wrT = (float*)((char*)d_ws + (size_t)S * PART);

    transpose_wrec<<<dim3(H_ / 32, H_ / 32), dim3(32, 8), 0, stream>>>(w_rec, wrT);

    dim3 ggrid(H_ / BN, (B_ * T_) / BM, S);
    const int rblocks = (int)(((size_t)B_ * T_ * H_ / 4 + 255) / 256);
    switch (S) {
        case 4:
            gemm_ff<4><<<ggrid, dim3(256), 0, stream>>>(x, w1, P);
            reduce_parts<4><<<dim3(rblocks), dim3(256), 0, stream>>>(P);
            break;
        case 2:
            gemm_ff<2><<<ggrid, dim3(256), 0, stream>>>(x, w1, P);
            reduce_parts<2><<<dim3(rblocks), dim3(256), 0, stream>>>(P);
            break;
        default:
            gemm_ff<1><<<ggrid, dim3(256), 0, stream>>>(x, w1, P);
            break;
    }
    snn_rec<<<dim3(B_), dim3(64), 0, stream>>>(P, wrT, w2, out);
}